// Round 16
// baseline (70.519 us; speedup 1.0000x reference)
//
#include <hip/hip_runtime.h>

#define HH 512
#define WW 512
#define HO 502
#define WO 502
#define KS 11
#define OTH 16                 // v-rows per tile (2 waves x 8)
#define RPT 8                  // v-rows per wave
#define NR  (RPT + KS - 1)     // 18 input rows per thread
#define OTW 48                 // output cols per tile
#define VW  58                 // v-cols = OTW + KS - 1
#define CPT 6                  // output cols per thread in phase 2 (8 groups x 6)
#define NPOS (CPT + KS - 1)    // 16 tap positions

#define NTX 11                 // x tiles (11*48 = 528 >= 502)
#define NTY 32                 // y tiles (32*16 = 512 >= 502)
#define NTILES (NTX * NTY)     // 352
#define NZ 48                  // B*C planes
#define TOTW (NTILES * NZ)     // 16896 tile-slices
#define NBLK 2816              // 11 blocks/CU x 256 CU (LDS 14.85KB -> 11 fit)
#define WQ (TOTW / NBLK)       // 6 exactly
#define WR (TOTW % NBLK)       // 0 -> perfect balance

typedef float f32x2 __attribute__((ext_vector_type(2)));

__device__ __forceinline__ float rfl(float x) {
    union { float f; int i; } u;
    u.f = x;
    u.i = __builtin_amdgcn_readfirstlane(u.i);
    return u.f;
}

// pad-free XOR-swizzled index (f32x2 units): bijective within [2][VW][16]
__device__ __forceinline__ int vidx(int ch, int col, int row) {
    return ch * (VW * 16) + col * 16 + (row ^ (col & 15));
}

// symmetric gaussian lookup, k compile-time
#define GW(k) g[(k) < 6 ? (k) : 10 - (k)]

__global__ __launch_bounds__(128)
void ssim_sep_kernel(
    const float* __restrict__ img1, const float* __restrict__ img2,
    const float* __restrict__ win, double* __restrict__ acc)
{
    // channel-paired intermediate: chp0 = {mu_s, mu_d}, chp1 = {E[s^2], E[d^2]}
    // Wave w exclusively owns v-rows [8w, 8w+8) -> no cross-wave deps, no barriers.
    __shared__ __align__(16) f32x2 vbuf2[2 * VW * 16];   // 14,848 B -> 11 blocks/CU
    __shared__ float wsum[2];

    const int tid = threadIdx.x;
    const int bid = blockIdx.x;

    // 1-D gaussian (wave-uniform -> SGPRs): g[k] = w[5][k]/sqrt(w[5][5]); symmetric
    float g[6];
    {
        double inv = 1.0 / sqrt((double)win[5 * KS + 5]);
        #pragma unroll
        for (int k = 0; k < 6; ++k)
            g[k] = rfl((float)((double)win[5 * KS + k] * inv));
    }

    // ---- fixed per-thread roles ----
    const int lane = tid & 63;              // phase-1 v column
    const int wv   = tid >> 6;              // wave id 0..1
    const int j0   = wv * RPT;              // first v-row owned by this wave (0 or 8)
    // phase-2 roles WITHIN-WAVE: own rows only
    const int rl = lane & 7;                // row within wave group
    const int cg = lane >> 3;               // col group 0..7
    const int c0 = cg * CPT;                // 0,6,...,42 ; max tap col 42+15=57=VW-1
    const int rowl = j0 + rl;               // local v-row for phase 2
    const size_t zstride = (size_t)HH * WW;
    const float c1 = 1e-4f, c2 = 9e-4f;     // L = 1 for [0,1) inputs

    // ---- work chunk: contiguous [w0, w0+cnt) of 16896 tile-slices ----
    int w0, cnt;
    if (bid < WR) { w0 = bid * (WQ + 1);            cnt = WQ + 1; }
    else          { w0 = WR * (WQ + 1) + (bid - WR) * WQ; cnt = WQ; }

    // issue global loads for work item w into a[]/b[]; s/d fold is DEFERRED to
    // the next iteration so the vmcnt wait lands after phase 2 (hidden).
    float a[NR], b[NR];
#define ISSUE_LOADS(wvv)                                               \
    {                                                                  \
        int z_   = (wvv) / NTILES;                                     \
        int rem_ = (wvv) % NTILES;                                     \
        int ty_  = rem_ / NTX;                                         \
        int tx_  = rem_ % NTX;                                         \
        const float* p1_ = img1 + (size_t)z_ * zstride;                \
        const float* p2_ = img2 + (size_t)z_ * zstride;                \
        int gc_ = tx_ * OTW + lane;                                    \
        if (gc_ > WW - 1) gc_ = WW - 1;                                \
        int r0_ = __builtin_amdgcn_readfirstlane(ty_ * OTH + j0);      \
        _Pragma("unroll")                                              \
        for (int ri = 0; ri < NR; ++ri) {                              \
            int gr = r0_ + ri;                                         \
            if (gr > HH - 1) gr = HH - 1;                              \
            size_t ro = (size_t)gr * WW + gc_;                         \
            a[ri] = p1_[ro];                                           \
            b[ri] = p2_[ro];                                           \
        }                                                              \
    }

    int w = w0;
    int ctx = (w % NTILES) % NTX;           // current tile coords (for output masks)
    int cty = (w % NTILES) / NTX;
    ISSUE_LOADS(w);

    float lsum = 0.f;

    for (int i = 0; i < cnt; ++i) {
        // ---------- fold s=a+b, d=a-b (loads issued ~1 item ago -> retired) ----------
        f32x2 sd[NR];
        #pragma unroll
        for (int ri = 0; ri < NR; ++ri)
            sd[ri] = (f32x2){a[ri] + b[ri], a[ri] - b[ri]};

        // ---------- phase 1: vertical conv, channel-paired pk math ----------
        f32x2 mu[RPT], es[RPT];             // {mu_s,mu_d}, {E[s2],E[d2]}
        #pragma unroll
        for (int j = 0; j < RPT; ++j) {
            mu[j] = (f32x2){0.f, 0.f};
            es[j] = (f32x2){0.f, 0.f};
        }
        #pragma unroll
        for (int ri = 0; ri < NR; ++ri) {
            f32x2 sv = sd[ri];
            f32x2 sq = sv * sv;             // pk_mul {s2, d2}
            #pragma unroll
            for (int j = 0; j < RPT; ++j) {
                int k = ri - j;
                if (k >= 0 && k < KS) {     // folds at compile time
                    float wk = GW(k);
                    mu[j] += wk * sv;       // pk_fma
                    es[j] += wk * sq;       // pk_fma
                }
            }
        }

        // own rows only -> no barrier; b64 writes, XOR-swizzled, conflict-free
        if (lane < VW) {
            #pragma unroll
            for (int j = 0; j < RPT; ++j) {
                vbuf2[vidx(0, lane, j0 + j)] = mu[j];
                vbuf2[vidx(1, lane, j0 + j)] = es[j];
            }
        }

        // issue next work item's loads; consumed only at next fold (after phase 2)
        int ntx = ctx, nty = cty;
        if (i + 1 < cnt) {
            int wn = w + 1;
            ntx = (wn % NTILES) % NTX;
            nty = (wn % NTILES) / NTX;
            ISSUE_LOADS(wn);
            w = wn;
        }

        // own ds_writes retired before own ds_reads; clobber pins ordering
        asm volatile("s_waitcnt lgkmcnt(0)" ::: "memory");

        // ---------- phase 2: horizontal conv + SSIM on OWN row ----------
        {
            f32x2 am[2][CPT];
            #pragma unroll
            for (int ch = 0; ch < 2; ++ch)
                #pragma unroll
                for (int j = 0; j < CPT; ++j) am[ch][j] = (f32x2){0.f, 0.f};

            #pragma unroll
            for (int ch = 0; ch < 2; ++ch) {
                #pragma unroll
                for (int t = 0; t < NPOS; ++t) {
                    f32x2 v = vbuf2[vidx(ch, c0 + t, rowl)];
                    #pragma unroll
                    for (int j = 0; j < CPT; ++j) {
                        int k = t - j;
                        if (k >= 0 && k < KS)        // folds at compile time
                            am[ch][j] += GW(k) * v;  // pk_fma
                    }
                }
            }

            const int orow = cty * OTH + rowl;
            if (orow < HO) {
                #pragma unroll
                for (int j = 0; j < CPT; ++j) {
                    int ocol = ctx * OTW + c0 + j;
                    if (ocol < WO) {
                        f32x2 m = am[0][j], e = am[1][j];
                        f32x2 sq = m * m;                  // {mus^2, mud^2}
                        float A   = 0.5f * (sq.x - sq.y);  // 2*mu1*mu2
                        float Bm  = 0.5f * (sq.x + sq.y);  // mu1^2 + mu2^2
                        float S12 = 0.5f * (e.x - e.y) - A;   // 2*sigma12
                        float SS  = 0.5f * (e.x + e.y) - Bm;  // sig1^2 + sig2^2
                        float num = (A + c1) * (S12 + c2);
                        float den = (Bm + c1) * (SS + c2);
                        lsum += num * __builtin_amdgcn_rcpf(den);
                    }
                }
            }
        }

        ctx = ntx; cty = nty;
    }

    // ---------- reduction (single barrier, once per block) ----------
    #pragma unroll
    for (int off = 32; off; off >>= 1)
        lsum += __shfl_down(lsum, off, 64);
    if ((tid & 63) == 0) wsum[wv] = lsum;
    __syncthreads();
    if (tid == 0) {
        double tt = (double)wsum[0] + (double)wsum[1];
        atomicAdd(acc, tt);
    }
}

__global__ void ssim_finalize(const double* __restrict__ acc,
                              float* __restrict__ out)
{
    out[0] = (float)(acc[0] / (double)(16LL * 3LL * (long long)HO * (long long)WO));
}

extern "C" void kernel_launch(void* const* d_in, const int* in_sizes, int n_in,
                              void* d_out, int out_size, void* d_ws, size_t ws_size,
                              hipStream_t stream) {
    const float* img1 = (const float*)d_in[0];
    const float* img2 = (const float*)d_in[1];
    const float* win  = (const float*)d_in[2];  // (3,1,11,11); channels identical
    float* out = (float*)d_out;
    double* acc = (double*)d_ws;

    hipMemsetAsync(acc, 0, sizeof(double), stream);

    ssim_sep_kernel<<<dim3(NBLK), 128, 0, stream>>>(img1, img2, win, acc);
    ssim_finalize<<<1, 1, 0, stream>>>(acc, out);
}

// Round 17
// 58.079 us; speedup vs baseline: 1.2142x; 1.2142x over previous
//
#include <hip/hip_runtime.h>

#define HH 512
#define WW 512
#define HO 502
#define WO 502
#define KS 11
#define OTH 32                 // v-rows per tile
#define RPT 8                  // v-rows per wave (4 waves)
#define NR  (RPT + KS - 1)     // 18 input rows per thread
#define OTW 48                 // output cols per tile
#define VW  58                 // v-cols = OTW + KS - 1
#define CSTR 33                // per-column stride in f32x2 (odd -> uniform banks)
#define CPT 6                  // output cols per thread in phase 2 (8 groups x 6)
#define NPOS (CPT + KS - 1)    // 16 tap positions

#define NTX 11                 // x tiles
#define NTY 16                 // y tiles
#define NTILES (NTX * NTY)     // 176
#define NZ 48                  // B*C planes
#define TOTW (NTILES * NZ)     // 8448 tile-slices
#define NBLK 1280              // 5 blocks/CU x 256 CU (proven R15)
#define WQ (TOTW / NBLK)       // 6
#define WR (TOTW % NBLK)       // 768 blocks take one extra

typedef float f32x2 __attribute__((ext_vector_type(2)));

__device__ __forceinline__ float rfl(float x) {
    union { float f; int i; } u;
    u.f = x;
    u.i = __builtin_amdgcn_readfirstlane(u.i);
    return u.f;
}

// symmetric gaussian lookup, k compile-time
#define GW(k) g[(k) < 6 ? (k) : 10 - (k)]

__global__ __launch_bounds__(256)
void ssim_sep_kernel(
    const float* __restrict__ img1, const float* __restrict__ img2,
    const float* __restrict__ win, double* __restrict__ acc)
{
    // channel-paired intermediate: chp0 = {mu_s, mu_d}, chp1 = {E[s^2], E[d^2]}
    // Wave w exclusively owns v-rows [8w, 8w+8) -> no cross-wave deps, no barriers.
    __shared__ __align__(16) f32x2 vbuf2[2][VW][CSTR];   // 30,624 B -> 5 blocks/CU
    __shared__ float wsum[4];

    const int tid = threadIdx.x;
    const int bid = blockIdx.x;

    // 1-D gaussian (wave-uniform -> SGPRs): g[k] = w[5][k]/sqrt(w[5][5]); symmetric
    float g[6];
    {
        double inv = 1.0 / sqrt((double)win[5 * KS + 5]);
        #pragma unroll
        for (int k = 0; k < 6; ++k)
            g[k] = rfl((float)((double)win[5 * KS + k] * inv));
    }

    // ---- fixed per-thread roles ----
    const int lane = tid & 63;              // phase-1 v column
    const int wv   = tid >> 6;              // wave id 0..3
    const int j0   = wv * RPT;              // first v-row owned by this wave
    const int rl = lane & 7;                // phase-2: row within wave group
    const int cg = lane >> 3;               // phase-2: col group 0..7
    const int c0 = cg * CPT;                // 0,6,...,42 ; max tap col 42+15=57=VW-1
    const int rowl = j0 + rl;               // local v-row for phase 2
    const float c1 = 1e-4f, c2 = 9e-4f;     // L = 1 for [0,1) inputs

    // ---- work chunk: contiguous [w0, w0+cnt) of 8448 tile-slices ----
    int w0, cnt;
    if (bid < WR) { w0 = bid * (WQ + 1);            cnt = WQ + 1; }
    else          { w0 = WR * (WQ + 1) + (bid - WR) * WQ; cnt = WQ; }

    // one-time decomposition; afterwards coordinates advance incrementally
    int z   = w0 / NTILES;
    int rem = w0 % NTILES;
    int ty  = rem / NTX;
    int tx  = rem % NTX;
    size_t zoff = (size_t)z * (HH * WW);
    size_t off0 = zoff + (size_t)ty * (OTH * WW) + (size_t)tx * OTW;
    int oy = ty * OTH, ox = tx * OTW;

    float a[NR], b[NR];

    // clamp-free fast path (interior tiles; 85%)
#define ISSUE_FAST()                                                  \
    {                                                                 \
        const float* pa_ = img1 + off0 + (j0 * WW) + lane;            \
        const float* pb_ = img2 + off0 + (j0 * WW) + lane;            \
        _Pragma("unroll")                                             \
        for (int ri = 0; ri < NR; ++ri) {                             \
            a[ri] = pa_[ri * WW];                                     \
            b[ri] = pb_[ri * WW];                                     \
        }                                                             \
    }
    // clamped path (edge tiles: tx==NTX-1 or ty==NTY-1)
#define ISSUE_EDGE()                                                  \
    {                                                                 \
        int gc_ = ox + lane; if (gc_ > WW - 1) gc_ = WW - 1;          \
        int r0_ = oy + j0;                                            \
        _Pragma("unroll")                                             \
        for (int ri = 0; ri < NR; ++ri) {                             \
            int gr_ = r0_ + ri; if (gr_ > HH - 1) gr_ = HH - 1;       \
            size_t ro_ = zoff + (size_t)gr_ * WW + gc_;               \
            a[ri] = img1[ro_];                                        \
            b[ri] = img2[ro_];                                        \
        }                                                             \
    }

    if (tx == NTX - 1 || ty == NTY - 1) { ISSUE_EDGE(); } else { ISSUE_FAST(); }

    float lsum = 0.f;

    for (int i = 0; i < cnt; ++i) {
        // ---------- fold s=a+b, d=a-b (loads issued ~1 item ago -> retired) ----------
        f32x2 sd[NR];
        #pragma unroll
        for (int ri = 0; ri < NR; ++ri)
            sd[ri] = (f32x2){a[ri] + b[ri], a[ri] - b[ri]};

        // ---------- phase 1: vertical conv, channel-paired pk math ----------
        f32x2 mu[RPT], es[RPT];             // {mu_s,mu_d}, {E[s2],E[d2]}
        #pragma unroll
        for (int j = 0; j < RPT; ++j) {
            mu[j] = (f32x2){0.f, 0.f};
            es[j] = (f32x2){0.f, 0.f};
        }
        #pragma unroll
        for (int ri = 0; ri < NR; ++ri) {
            f32x2 sv = sd[ri];
            f32x2 sq = sv * sv;             // pk_mul {s2, d2}
            #pragma unroll
            for (int j = 0; j < RPT; ++j) {
                int k = ri - j;
                if (k >= 0 && k < KS) {     // folds at compile time
                    float wk = GW(k);
                    mu[j] += wk * sv;       // pk_fma
                    es[j] += wk * sq;       // pk_fma
                }
            }
        }

        // own rows only -> no barrier; b64 writes, conflict-free
        if (lane < VW) {
            #pragma unroll
            for (int j = 0; j < RPT; ++j) {
                vbuf2[0][lane][j0 + j] = mu[j];
                vbuf2[1][lane][j0 + j] = es[j];
            }
        }

        // snapshot current-item output coords for phase-2 masks
        const int oyc = oy, oxc = ox;

        // advance state incrementally + issue next item's loads
        if (i + 1 < cnt) {
            tx++; off0 += OTW; ox += OTW;
            if (tx == NTX) {
                tx = 0; ox = 0;
                off0 += (size_t)(OTH * WW) - (size_t)(NTX * OTW);
                ty++; oy += OTH;
                if (ty == NTY) {
                    ty = 0; oy = 0;
                    zoff += (size_t)(HH * WW);
                    off0 = zoff;
                }
            }
            if (tx == NTX - 1 || ty == NTY - 1) { ISSUE_EDGE(); } else { ISSUE_FAST(); }
        }

        // own ds_writes retired before own ds_reads; clobber pins ordering
        asm volatile("s_waitcnt lgkmcnt(0)" ::: "memory");

        // ---------- phase 2: horizontal conv + SSIM on OWN row ----------
        {
            f32x2 am[2][CPT];
            #pragma unroll
            for (int ch = 0; ch < 2; ++ch)
                #pragma unroll
                for (int j = 0; j < CPT; ++j) am[ch][j] = (f32x2){0.f, 0.f};

            #pragma unroll
            for (int ch = 0; ch < 2; ++ch) {
                #pragma unroll
                for (int t = 0; t < NPOS; ++t) {
                    f32x2 v = vbuf2[ch][c0 + t][rowl];
                    #pragma unroll
                    for (int j = 0; j < CPT; ++j) {
                        int k = t - j;
                        if (k >= 0 && k < KS)        // folds at compile time
                            am[ch][j] += GW(k) * v;  // pk_fma
                    }
                }
            }

            const int orow = oyc + rowl;
            if (orow < HO) {
                #pragma unroll
                for (int j = 0; j < CPT; ++j) {
                    int ocol = oxc + c0 + j;
                    if (ocol < WO) {
                        f32x2 m = am[0][j], e = am[1][j];
                        f32x2 sq = m * m;                  // {mus^2, mud^2}
                        float A   = 0.5f * (sq.x - sq.y);  // 2*mu1*mu2
                        float Bm  = 0.5f * (sq.x + sq.y);  // mu1^2 + mu2^2
                        float S12 = 0.5f * (e.x - e.y) - A;   // 2*sigma12
                        float SS  = 0.5f * (e.x + e.y) - Bm;  // sig1^2 + sig2^2
                        float num = (A + c1) * (S12 + c2);
                        float den = (Bm + c1) * (SS + c2);
                        lsum += num * __builtin_amdgcn_rcpf(den);
                    }
                }
            }
        }
    }

    // ---------- reduction (single barrier, once per block) ----------
    #pragma unroll
    for (int off = 32; off; off >>= 1)
        lsum += __shfl_down(lsum, off, 64);
    if ((tid & 63) == 0) wsum[wv] = lsum;
    __syncthreads();
    if (tid == 0) {
        double tt = (double)wsum[0] + (double)wsum[1] +
                    (double)wsum[2] + (double)wsum[3];
        atomicAdd(acc, tt);
    }
}

__global__ void ssim_finalize(const double* __restrict__ acc,
                              float* __restrict__ out)
{
    out[0] = (float)(acc[0] / (double)(16LL * 3LL * (long long)HO * (long long)WO));
}

extern "C" void kernel_launch(void* const* d_in, const int* in_sizes, int n_in,
                              void* d_out, int out_size, void* d_ws, size_t ws_size,
                              hipStream_t stream) {
    const float* img1 = (const float*)d_in[0];
    const float* img2 = (const float*)d_in[1];
    const float* win  = (const float*)d_in[2];  // (3,1,11,11); channels identical
    float* out = (float*)d_out;
    double* acc = (double*)d_ws;

    hipMemsetAsync(acc, 0, sizeof(double), stream);

    ssim_sep_kernel<<<dim3(NBLK), 256, 0, stream>>>(img1, img2, win, acc);
    ssim_finalize<<<1, 1, 0, stream>>>(acc, out);
}